// Round 5
// baseline (1010.727 us; speedup 1.0000x reference)
//
#include <hip/hip_runtime.h>
#include <math.h>

#define N_NODES 131072
#define N_EDGES 2097152
#define DIM     64
#define BSUB    4096
#define NREL    3
#define NBASES  2
#define KDIM    192   // NB*64 basis slots + 64 self-loop

typedef unsigned short u16;

__device__ __forceinline__ float bf2f(u16 x) {
    return __uint_as_float(((unsigned)x) << 16);
}
__device__ __forceinline__ u16 f2bf(float f) {
    unsigned u = __float_as_uint(f);
    unsigned r = (u + 0x7FFFu + ((u >> 16) & 1u)) >> 16;   // RNE
    return (u16)r;
}
__device__ __forceinline__ float4 bf4_to_f4(ushort4 u) {
    return make_float4(bf2f(u.x), bf2f(u.y), bf2f(u.z), bf2f(u.w));
}
__device__ __forceinline__ ushort4 f4_to_bf4(float4 v) {
    ushort4 o; o.x = f2bf(v.x); o.y = f2bf(v.y); o.z = f2bf(v.z); o.w = f2bf(v.w);
    return o;
}

// ---------------- CSR build ----------------

__global__ void zero_kernel(int* __restrict__ p, int n) {
    int i = blockIdx.x * 256 + threadIdx.x;
    if (i < n) p[i] = 0;
}

__global__ void hist_kernel(const int* __restrict__ dst, int* __restrict__ cnt) {
    int e = blockIdx.x * 256 + threadIdx.x;
    if (e < N_EDGES) atomicAdd(&cnt[dst[e]], 1);
}

__global__ void scan1_kernel(const int* __restrict__ cnt, int* __restrict__ scanned,
                             int* __restrict__ bsum) {
    __shared__ int s[256];
    int tid = threadIdx.x;
    int i = blockIdx.x * 256 + tid;
    int v = cnt[i];
    s[tid] = v;
    __syncthreads();
    int val = v;
    for (int off = 1; off < 256; off <<= 1) {
        int tmp = (tid >= off) ? s[tid - off] : 0;
        __syncthreads();
        val += tmp;
        s[tid] = val;
        __syncthreads();
    }
    scanned[i] = val - v;                 // exclusive
    if (tid == 255) bsum[blockIdx.x] = val;
}

__global__ void scan2_kernel(int* __restrict__ bsum) {
    __shared__ int s[512];
    int tid = threadIdx.x;
    int v = bsum[tid];
    s[tid] = v;
    __syncthreads();
    int val = v;
    for (int off = 1; off < 512; off <<= 1) {
        int tmp = (tid >= off) ? s[tid - off] : 0;
        __syncthreads();
        val += tmp;
        s[tid] = val;
        __syncthreads();
    }
    bsum[tid] = val - v;
}

__global__ void scan3_kernel(int* __restrict__ offs, const int* __restrict__ bsum,
                             int* __restrict__ cursor) {
    int i = blockIdx.x * 256 + threadIdx.x;
    int v = offs[i] + bsum[blockIdx.x];
    offs[i] = v;
    cursor[i] = v;
    if (i == 0) offs[N_NODES] = N_EDGES;
}

// scatter edges into CSR order; ONE 16B store per edge
__global__ void fill_kernel(const int* __restrict__ src, const int* __restrict__ dst,
                            const int* __restrict__ et, const float* __restrict__ m1,
                            const float* __restrict__ m2, int* __restrict__ cursor,
                            int4* __restrict__ csr) {
    int e = blockIdx.x * 256 + threadIdx.x;
    if (e >= N_EDGES) return;
    int d = dst[e];
    int p = atomicAdd(&cursor[d], 1);
    int4 v;
    v.x = src[e] | (et[e] << 20);
    v.y = __float_as_int(m1[e]);
    v.z = __float_as_int(m2[e]);
    v.w = 0;
    csr[p] = v;
}

// ---------------- x -> bf16 convert ----------------
__global__ void cvt_kernel(const float4* __restrict__ x, ushort4* __restrict__ hb, int n4) {
    int i = blockIdx.x * 256 + threadIdx.x;
    if (i < n4) hb[i] = f4_to_bf4(x[i]);
}

// ---------------- weight stacking ----------------
// wstk[conv][192][64]: rows 0..63 = V_b0, 64..127 = V_b1, 128..191 = W_self
__global__ void wstk_kernel(const float* __restrict__ lV, const float* __restrict__ lW,
                            const float* __restrict__ gV, const float* __restrict__ gW,
                            float* __restrict__ wstk) {
    int idx = blockIdx.x * 256 + threadIdx.x;   // 6*192*64 total
    if (idx >= 6 * KDIM * DIM) return;
    int o = idx & 63;
    int r = (idx >> 6) % KDIM;
    int c = idx / (KDIM * DIM);   // conv 0..5
    int layer = c >> 1;
    bool isglobal = c & 1;
    const float* V = isglobal ? gV : lV;
    const float* W = isglobal ? gW : lW;
    float val;
    if (r < NBASES * DIM) {
        int b = r >> 6, d = r & 63;
        val = V[((layer * NBASES + b) * DIM + d) * DIM + o];
    } else {
        int d = r - NBASES * DIM;
        val = W[(layer * DIM + d) * DIM + o];
    }
    wstk[idx] = val;
}

// ---------------- edge aggregation (wave per dst node, basis-space, bf16 h) ------
// h: bf16 [N,64] as ushort4 (16 per row). t: bf16 [n,192] as ushort4 (48 per row).
// Deep-pipelined gathers: per 32-edge group, 8 independent wave-loads (each load
// covers 4 edges: quarter q's 16 lanes fetch edge j+4s+q's 128B row) are issued
// back-to-back before any FMA consumes them -> 8 gathers in flight per wave.
// which: 0 -> use m1 (csr.y), 1 -> use m2 (csr.z)
__global__ __launch_bounds__(256) void agg_kernel(
    const ushort4* __restrict__ hb, const int* __restrict__ offs,
    const int4* __restrict__ csr, const float* __restrict__ Cc,
    int which, ushort4* __restrict__ t, int nNodes) {
    int lane = threadIdx.x & 63;
    int n = (blockIdx.x << 2) + (threadIdx.x >> 6);
    if (n >= nNodes) return;
    int q  = lane >> 4;     // quarter 0..3
    int ql = lane & 15;     // lane within quarter
    float Ca0 = Cc[0], Cb0 = Cc[1], Ca1 = Cc[2], Cb1 = Cc[3], Ca2 = Cc[4], Cb2 = Cc[5];
    int beg = offs[n], end = offs[n + 1];
    float4 a0 = make_float4(0.f, 0.f, 0.f, 0.f);
    float4 a1 = make_float4(0.f, 0.f, 0.f, 0.f);
    for (int base = beg; base < end; base += 64) {
        int cnt = min(64, end - base);
        int p = 0; float m = 0.f;
        if (lane < cnt) {
            int4 meta = csr[base + lane];
            p = meta.x;
            m = __int_as_float(which ? meta.z : meta.y);
        }
        for (int j = 0; j < cnt; j += 32) {
            int pe[8]; float me[8]; ushort4 r[8];
            // broadcast metadata for this quarter's 8 edges (j+4s+q)
#pragma unroll
            for (int s = 0; s < 8; s++) {
                int jj = j + (s << 2) + q;
                int idx = jj < cnt ? jj : 0;
                pe[s] = __shfl(p, idx, 64);
                float mm = __shfl(m, idx, 64);
                me[s] = jj < cnt ? mm : 0.f;
            }
            // issue all 8 gathers before consuming any
#pragma unroll
            for (int s = 0; s < 8; s++)
                r[s] = hb[((pe[s] & 0xFFFFF) << 4) + ql];
            // consume
#pragma unroll
            for (int s = 0; s < 8; s++) {
                float4 v = bf4_to_f4(r[s]);
                int et = pe[s] >> 20;
                float ca = et == 0 ? Ca0 : (et == 1 ? Ca1 : Ca2);
                float cb = et == 0 ? Cb0 : (et == 1 ? Cb1 : Cb2);
                float c0 = me[s] * ca, c1 = me[s] * cb;
                a0.x = fmaf(c0, v.x, a0.x); a0.y = fmaf(c0, v.y, a0.y);
                a0.z = fmaf(c0, v.z, a0.z); a0.w = fmaf(c0, v.w, a0.w);
                a1.x = fmaf(c1, v.x, a1.x); a1.y = fmaf(c1, v.y, a1.y);
                a1.z = fmaf(c1, v.z, a1.z); a1.w = fmaf(c1, v.w, a1.w);
            }
        }
    }
    // butterfly-sum the 4 quarters
#pragma unroll
    for (int off = 16; off < 64; off <<= 1) {
        a0.x += __shfl_xor(a0.x, off, 64); a0.y += __shfl_xor(a0.y, off, 64);
        a0.z += __shfl_xor(a0.z, off, 64); a0.w += __shfl_xor(a0.w, off, 64);
        a1.x += __shfl_xor(a1.x, off, 64); a1.y += __shfl_xor(a1.y, off, 64);
        a1.z += __shfl_xor(a1.z, off, 64); a1.w += __shfl_xor(a1.w, off, 64);
    }
    // write t row: lanes 0-15 -> u_b0, 16-31 -> u_b1, 32-47 -> h[n] (bf16 passthrough)
    ushort4 outv;
    if (q == 0)      outv = f4_to_bf4(a0);
    else if (q == 1) outv = f4_to_bf4(a1);
    else             outv = hb[(n << 4) + ql];
    if (q < 3)
        t[(size_t)n * 48 + (q << 4) + ql] = outv;
}

// ---------------- GEMM [nRows,192(bf16)] @ [192,64(f32)] + bias + activation -----
// act: 0 = elu, 1 = leaky_relu(0.01). Tile 128 rows/block, 256 threads.
// hout: bf16 [nRows,64]; subg (optional): fp32 [BSUB,192] slice.
__global__ __launch_bounds__(256) void gemm_kernel(
    const ushort4* __restrict__ t, const float* __restrict__ W,
    const float* __restrict__ bias, ushort4* __restrict__ hout,
    float* __restrict__ subg, int subg_off, int nRows, int act) {
    __shared__ float As[128][33];
    __shared__ float Ws[32][64];
    int tid = threadIdx.x;
    long row0 = (long)blockIdx.x * 128;
    int rgrp = (tid & 3) | ((tid >> 6) << 2);   // 0..15 -> rows rgrp*8..+7
    int c0 = ((tid >> 2) & 15) << 2;            // 4 cols
    float acc[8][4];
#pragma unroll
    for (int i = 0; i < 8; i++) {
        acc[i][0] = 0.f; acc[i][1] = 0.f; acc[i][2] = 0.f; acc[i][3] = 0.f;
    }
    for (int k0 = 0; k0 < KDIM; k0 += 32) {
        __syncthreads();
        // stage A chunk: 128 rows x 32 k (bf16 -> f32); 8 ushort4 per row-chunk
#pragma unroll
        for (int l = 0; l < 4; l++) {
            int f = l * 256 + tid;
            int r = f >> 3, kk4 = f & 7;
            long gr = row0 + r;
            float4 v = make_float4(0.f, 0.f, 0.f, 0.f);
            if (gr < nRows) v = bf4_to_f4(t[gr * 48 + (k0 >> 2) + kk4]);
            int kk = kk4 << 2;
            As[r][kk] = v.x; As[r][kk + 1] = v.y; As[r][kk + 2] = v.z; As[r][kk + 3] = v.w;
        }
        // stage W chunk: 32x64
#pragma unroll
        for (int l = 0; l < 2; l++) {
            int f = l * 256 + tid;
            int kk = f >> 4, col = (f & 15) << 2;
            *(float4*)&Ws[kk][col] = *(const float4*)&W[(k0 + kk) * 64 + col];
        }
        __syncthreads();
#pragma unroll
        for (int kk = 0; kk < 32; kk++) {
            float4 w = *(float4*)&Ws[kk][c0];
#pragma unroll
            for (int rr = 0; rr < 8; rr++) {
                float a = As[rgrp * 8 + rr][kk];
                acc[rr][0] = fmaf(a, w.x, acc[rr][0]);
                acc[rr][1] = fmaf(a, w.y, acc[rr][1]);
                acc[rr][2] = fmaf(a, w.z, acc[rr][2]);
                acc[rr][3] = fmaf(a, w.w, acc[rr][3]);
            }
        }
    }
    float4 bb = *(const float4*)&bias[c0];
#pragma unroll
    for (int rr = 0; rr < 8; rr++) {
        long row = row0 + rgrp * 8 + rr;
        if (row >= nRows) continue;
        float v[4] = {acc[rr][0] + bb.x, acc[rr][1] + bb.y,
                      acc[rr][2] + bb.z, acc[rr][3] + bb.w};
#pragma unroll
        for (int j = 0; j < 4; j++) {
            float x = v[j];
            v[j] = act ? (x > 0.f ? x : 0.01f * x)
                       : (x > 0.f ? x : expm1f(x));
        }
        float4 o = make_float4(v[0], v[1], v[2], v[3]);
        hout[row * 16 + (c0 >> 2)] = f4_to_bf4(o);
        if (subg && row < BSUB)
            *(float4*)&subg[row * 192 + subg_off + c0] = o;
    }
}

// ---------------- MLP head: [4096,192] -> relu 128 -> sigmoid 1 ----------------
__global__ __launch_bounds__(256) void head_kernel(
    const float* __restrict__ subg, const float* __restrict__ w1,
    const float* __restrict__ b1, const float* __restrict__ w2,
    const float* __restrict__ b2, float* __restrict__ out) {
    __shared__ float srow[4][192];
    int lane = threadIdx.x & 63, wid = threadIdx.x >> 6;
    int row = blockIdx.x * 4 + wid;
    const float* sr = subg + (size_t)row * 192;
    srow[wid][lane] = sr[lane];
    srow[wid][64 + lane] = sr[64 + lane];
    srow[wid][128 + lane] = sr[128 + lane];
    __syncthreads();
    float acc1 = b1[lane], acc2 = b1[64 + lane];
    const float* w1a = w1 + lane * 192;
    const float* w1b = w1 + (64 + lane) * 192;
    for (int k = 0; k < 192; k++) {
        float s = srow[wid][k];
        acc1 = fmaf(s, w1a[k], acc1);
        acc2 = fmaf(s, w1b[k], acc2);
    }
    acc1 = fmaxf(acc1, 0.f);
    acc2 = fmaxf(acc2, 0.f);
    float part = acc1 * w2[lane] + acc2 * w2[64 + lane];
    for (int off = 32; off; off >>= 1) part += __shfl_down(part, off, 64);
    if (lane == 0) out[row] = 1.f / (1.f + expf(-(part + b2[0])));
}

extern "C" void kernel_launch(void* const* d_in, const int* in_sizes, int n_in,
                              void* d_out, int out_size, void* d_ws, size_t ws_size,
                              hipStream_t stream) {
    const float* x     = (const float*)d_in[0];
    const int*   src   = (const int*)d_in[1];
    const int*   dst   = (const int*)d_in[2];
    const int*   etype = (const int*)d_in[3];
    const float* mask  = (const float*)d_in[4];
    const float* mask2 = (const float*)d_in[5];
    const float* lV = (const float*)d_in[6];
    const float* lC = (const float*)d_in[7];
    const float* lW = (const float*)d_in[8];
    const float* lB = (const float*)d_in[9];
    const float* gV = (const float*)d_in[10];
    const float* gC = (const float*)d_in[11];
    const float* gW = (const float*)d_in[12];
    const float* gB = (const float*)d_in[13];
    const float* w1 = (const float*)d_in[14];
    const float* b1 = (const float*)d_in[15];
    const float* w2 = (const float*)d_in[16];
    const float* b2 = (const float*)d_in[17];
    float* out = (float*)d_out;

    // workspace carve-up
    char* ws = (char*)d_ws;
    size_t off = 0;
    auto alloc = [&](size_t bytes) {
        void* p = ws + off;
        off += (bytes + 255) & ~(size_t)255;
        return p;
    };
    ushort4* h    = (ushort4*)alloc((size_t)N_NODES * 64 * 2);     // bf16 [N,64]
    ushort4* t    = (ushort4*)alloc((size_t)N_NODES * KDIM * 2);   // bf16 [N,192]
    int4*  csr    = (int4*)alloc((size_t)N_EDGES * 16);
    int*   offs   = (int*)alloc((size_t)(N_NODES + 1) * 4);
    int*   cursor = (int*)alloc((size_t)N_NODES * 4);
    int*   bsum   = (int*)alloc(512 * 4);
    float* wstk   = (float*)alloc((size_t)6 * KDIM * DIM * 4);
    float* subg   = (float*)alloc((size_t)BSUB * 192 * 4);

    // CSR build (cursor doubles as count buffer)
    zero_kernel<<<N_NODES / 256, 256, 0, stream>>>(cursor, N_NODES);
    hist_kernel<<<N_EDGES / 256, 256, 0, stream>>>(dst, cursor);
    scan1_kernel<<<N_NODES / 256, 256, 0, stream>>>(cursor, offs, bsum);
    scan2_kernel<<<1, 512, 0, stream>>>(bsum);
    scan3_kernel<<<N_NODES / 256, 256, 0, stream>>>(offs, bsum, cursor);
    fill_kernel<<<N_EDGES / 256, 256, 0, stream>>>(src, dst, etype, mask, mask2,
                                                   cursor, csr);
    wstk_kernel<<<(6 * KDIM * DIM + 255) / 256, 256, 0, stream>>>(lV, lW, gV, gW, wstk);
    cvt_kernel<<<(N_NODES * 64 / 4) / 256, 256, 0, stream>>>((const float4*)x, h,
                                                             N_NODES * 64 / 4);

    for (int layer = 0; layer < 3; layer++) {
        // local conv (mask, elu)
        agg_kernel<<<N_NODES / 4, 256, 0, stream>>>(h, offs, csr,
                                                    lC + layer * NREL * NBASES, 0, t, N_NODES);
        gemm_kernel<<<N_NODES / 128, 256, 0, stream>>>(
            t, wstk + (size_t)(layer * 2 + 0) * KDIM * DIM, lB + layer * 64,
            h, nullptr, 0, N_NODES, 0);
        // global conv (mask2, leaky_relu); last layer only needs subgraph rows
        int nG = (layer == 2) ? BSUB : N_NODES;
        agg_kernel<<<(nG + 3) / 4, 256, 0, stream>>>(h, offs, csr,
                                                     gC + layer * NREL * NBASES, 1, t, nG);
        gemm_kernel<<<(nG + 127) / 128, 256, 0, stream>>>(
            t, wstk + (size_t)(layer * 2 + 1) * KDIM * DIM, gB + layer * 64,
            h, subg, layer * 64, nG, 1);
    }
    head_kernel<<<BSUB / 4, 256, 0, stream>>>(subg, w1, b1, w2, b2, out);
}

// Round 6
// 823.110 us; speedup vs baseline: 1.2279x; 1.2279x over previous
//
#include <hip/hip_runtime.h>
#include <math.h>

#define N_NODES 131072
#define N_EDGES 2097152
#define DIM     64
#define BSUB    4096
#define NREL    3
#define NBASES  2
#define KDIM    192   // NB*64 basis slots + 64 self-loop

typedef unsigned short u16;
typedef __attribute__((ext_vector_type(8))) short bf16x8;   // MFMA A/B frag (4 VGPRs)
typedef __attribute__((ext_vector_type(4))) float f32x4;    // MFMA C/D frag

__device__ __forceinline__ float bf2f(u16 x) {
    return __uint_as_float(((unsigned)x) << 16);
}
__device__ __forceinline__ u16 f2bf(float f) {
    unsigned u = __float_as_uint(f);
    unsigned r = (u + 0x7FFFu + ((u >> 16) & 1u)) >> 16;   // RNE
    return (u16)r;
}
__device__ __forceinline__ float4 bf4_to_f4(ushort4 u) {
    return make_float4(bf2f(u.x), bf2f(u.y), bf2f(u.z), bf2f(u.w));
}
__device__ __forceinline__ ushort4 f4_to_bf4(float4 v) {
    ushort4 o; o.x = f2bf(v.x); o.y = f2bf(v.y); o.z = f2bf(v.z); o.w = f2bf(v.w);
    return o;
}

// ---------------- CSR build ----------------

__global__ void zero_kernel(int* __restrict__ p, int n) {
    int i = blockIdx.x * 256 + threadIdx.x;
    if (i < n) p[i] = 0;
}

__global__ void hist_kernel(const int* __restrict__ dst, int* __restrict__ cnt) {
    int e = blockIdx.x * 256 + threadIdx.x;
    if (e < N_EDGES) atomicAdd(&cnt[dst[e]], 1);
}

__global__ void scan1_kernel(const int* __restrict__ cnt, int* __restrict__ scanned,
                             int* __restrict__ bsum) {
    __shared__ int s[256];
    int tid = threadIdx.x;
    int i = blockIdx.x * 256 + tid;
    int v = cnt[i];
    s[tid] = v;
    __syncthreads();
    int val = v;
    for (int off = 1; off < 256; off <<= 1) {
        int tmp = (tid >= off) ? s[tid - off] : 0;
        __syncthreads();
        val += tmp;
        s[tid] = val;
        __syncthreads();
    }
    scanned[i] = val - v;                 // exclusive
    if (tid == 255) bsum[blockIdx.x] = val;
}

__global__ void scan2_kernel(int* __restrict__ bsum) {
    __shared__ int s[512];
    int tid = threadIdx.x;
    int v = bsum[tid];
    s[tid] = v;
    __syncthreads();
    int val = v;
    for (int off = 1; off < 512; off <<= 1) {
        int tmp = (tid >= off) ? s[tid - off] : 0;
        __syncthreads();
        val += tmp;
        s[tid] = val;
        __syncthreads();
    }
    bsum[tid] = val - v;
}

__global__ void scan3_kernel(int* __restrict__ offs, const int* __restrict__ bsum,
                             int* __restrict__ cursor) {
    int i = blockIdx.x * 256 + threadIdx.x;
    int v = offs[i] + bsum[blockIdx.x];
    offs[i] = v;
    cursor[i] = v;
    if (i == 0) offs[N_NODES] = N_EDGES;
}

// scatter edges into CSR order; ONE 16B store per edge
__global__ void fill_kernel(const int* __restrict__ src, const int* __restrict__ dst,
                            const int* __restrict__ et, const float* __restrict__ m1,
                            const float* __restrict__ m2, int* __restrict__ cursor,
                            int4* __restrict__ csr) {
    int e = blockIdx.x * 256 + threadIdx.x;
    if (e >= N_EDGES) return;
    int d = dst[e];
    int p = atomicAdd(&cursor[d], 1);
    int4 v;
    v.x = src[e] | (et[e] << 20);
    v.y = __float_as_int(m1[e]);
    v.z = __float_as_int(m2[e]);
    v.w = 0;
    csr[p] = v;
}

// ---------------- x -> bf16 convert ----------------
__global__ void cvt_kernel(const float4* __restrict__ x, ushort4* __restrict__ hb, int n4) {
    int i = blockIdx.x * 256 + threadIdx.x;
    if (i < n4) hb[i] = f4_to_bf4(x[i]);
}

// ---------------- weight packing into MFMA B-fragment layout ----------------
// Combined per-conv weight Wc[192][64]: rows 0..63 = V_b0, 64..127 = V_b1,
// 128..191 = W_self. Packed bf16 frag buffer layout:
//   wfrag[conv][nt(4)][kidx(6)][lane(64)][j(8)]
// where for lane: n = nt*16 + (lane&15), k = kidx*32 + (lane>>4)*8 + j.
// One thread per (conv, nt, kidx, lane) writes 8 bf16 (16 B).
__global__ void wpack_kernel(const float* __restrict__ lV, const float* __restrict__ lW,
                             const float* __restrict__ gV, const float* __restrict__ gW,
                             u16* __restrict__ wfrag) {
    int idx = blockIdx.x * 256 + threadIdx.x;   // 6*4*6*64 = 9216
    if (idx >= 6 * 4 * 6 * 64) return;
    int lane = idx & 63;
    int kidx = (idx >> 6) % 6;
    int nt   = (idx >> 6) / 6 % 4;
    int c    = idx / (64 * 6 * 4);      // conv 0..5
    int layer = c >> 1;
    bool isglobal = c & 1;
    const float* V = isglobal ? gV : lV;
    const float* W = isglobal ? gW : lW;
    int n = nt * 16 + (lane & 15);
    int kbase = kidx * 32 + (lane >> 4) * 8;
    u16 vals[8];
#pragma unroll
    for (int j = 0; j < 8; j++) {
        int r = kbase + j;      // 0..191
        float val;
        if (r < NBASES * DIM) {
            int b = r >> 6, d = r & 63;
            val = V[((layer * NBASES + b) * DIM + d) * DIM + n];
        } else {
            int d = r - NBASES * DIM;
            val = W[(layer * DIM + d) * DIM + n];
        }
        vals[j] = f2bf(val);
    }
    ushort4* o = (ushort4*)(wfrag + (size_t)idx * 8);
    o[0] = make_ushort4(vals[0], vals[1], vals[2], vals[3]);
    o[1] = make_ushort4(vals[4], vals[5], vals[6], vals[7]);
}

// ---------------- edge aggregation (wave per dst node, basis-space, bf16 h) ------
// h: bf16 [N,64] as ushort4 (16 per row). t: bf16 [n,192] as ushort4 (48 per row).
// which: 0 -> use m1 (csr.y), 1 -> use m2 (csr.z)
__global__ __launch_bounds__(256) void agg_kernel(
    const ushort4* __restrict__ hb, const int* __restrict__ offs,
    const int4* __restrict__ csr, const float* __restrict__ Cc,
    int which, ushort4* __restrict__ t, int nNodes) {
    int lane = threadIdx.x & 63;
    int n = (blockIdx.x << 2) + (threadIdx.x >> 6);
    if (n >= nNodes) return;
    int q  = lane >> 4;     // quarter 0..3
    int ql = lane & 15;     // lane within quarter
    float Ca0 = Cc[0], Cb0 = Cc[1], Ca1 = Cc[2], Cb1 = Cc[3], Ca2 = Cc[4], Cb2 = Cc[5];
    int beg = offs[n], end = offs[n + 1];
    float4 a0 = make_float4(0.f, 0.f, 0.f, 0.f);
    float4 a1 = make_float4(0.f, 0.f, 0.f, 0.f);
    for (int base = beg; base < end; base += 64) {
        int cnt = min(64, end - base);
        int p = 0; float m = 0.f;
        if (lane < cnt) {
            int4 meta = csr[base + lane];
            p = meta.x;
            m = __int_as_float(which ? meta.z : meta.y);
        }
        for (int j = 0; j < cnt; j += 32) {
            int pe[8]; float me[8]; ushort4 r[8];
#pragma unroll
            for (int s = 0; s < 8; s++) {
                int jj = j + (s << 2) + q;
                int idx = jj < cnt ? jj : 0;
                pe[s] = __shfl(p, idx, 64);
                float mm = __shfl(m, idx, 64);
                me[s] = jj < cnt ? mm : 0.f;
            }
#pragma unroll
            for (int s = 0; s < 8; s++)
                r[s] = hb[((pe[s] & 0xFFFFF) << 4) + ql];
#pragma unroll
            for (int s = 0; s < 8; s++) {
                float4 v = bf4_to_f4(r[s]);
                int et = pe[s] >> 20;
                float ca = et == 0 ? Ca0 : (et == 1 ? Ca1 : Ca2);
                float cb = et == 0 ? Cb0 : (et == 1 ? Cb1 : Cb2);
                float c0 = me[s] * ca, c1 = me[s] * cb;
                a0.x = fmaf(c0, v.x, a0.x); a0.y = fmaf(c0, v.y, a0.y);
                a0.z = fmaf(c0, v.z, a0.z); a0.w = fmaf(c0, v.w, a0.w);
                a1.x = fmaf(c1, v.x, a1.x); a1.y = fmaf(c1, v.y, a1.y);
                a1.z = fmaf(c1, v.z, a1.z); a1.w = fmaf(c1, v.w, a1.w);
            }
        }
    }
#pragma unroll
    for (int off = 16; off < 64; off <<= 1) {
        a0.x += __shfl_xor(a0.x, off, 64); a0.y += __shfl_xor(a0.y, off, 64);
        a0.z += __shfl_xor(a0.z, off, 64); a0.w += __shfl_xor(a0.w, off, 64);
        a1.x += __shfl_xor(a1.x, off, 64); a1.y += __shfl_xor(a1.y, off, 64);
        a1.z += __shfl_xor(a1.z, off, 64); a1.w += __shfl_xor(a1.w, off, 64);
    }
    ushort4 outv;
    if (q == 0)      outv = f4_to_bf4(a0);
    else if (q == 1) outv = f4_to_bf4(a1);
    else             outv = hb[(n << 4) + ql];
    if (q < 3)
        t[(size_t)n * 48 + (q << 4) + ql] = outv;
}

// ---------------- MFMA GEMM [nRows,192(bf16)] @ [192,64(bf16 frag)] -------------
// 256 threads = 4 waves; wave w owns rows blockIdx*64 + w*16 .. +15, all 64 cols.
// 4 accumulators (n-tiles of 16), K-loop of 6 x mfma_f32_16x16x32_bf16.
// A-frag: lane (quad=lane>>4, l16=lane&15) holds t[row0+l16][kidx*32+quad*8 .. +7].
// B-frag: prepacked (wpack_kernel). C/D: col=l16+nt*16, row=quad*4+reg.
// act: 0 = elu, 1 = leaky_relu(0.01). No LDS, no barriers.
__global__ __launch_bounds__(256) void gemm_kernel(
    const u16* __restrict__ t, const u16* __restrict__ wfrag,
    const float* __restrict__ bias, u16* __restrict__ hout,
    float* __restrict__ subg, int subg_off, int nRows, int act) {
    int tid = threadIdx.x;
    int wave = tid >> 6, lane = tid & 63;
    int l16 = lane & 15, quad = lane >> 4;
    int row0 = blockIdx.x * 64 + wave * 16;
    const u16* trow = t + (size_t)(row0 + l16) * KDIM;
    f32x4 acc0 = {0.f, 0.f, 0.f, 0.f};
    f32x4 acc1 = {0.f, 0.f, 0.f, 0.f};
    f32x4 acc2 = {0.f, 0.f, 0.f, 0.f};
    f32x4 acc3 = {0.f, 0.f, 0.f, 0.f};
#pragma unroll
    for (int kidx = 0; kidx < 6; kidx++) {
        bf16x8 a = *(const bf16x8*)(trow + kidx * 32 + quad * 8);
        bf16x8 b0 = *(const bf16x8*)(wfrag + ((size_t)(0 * 6 + kidx) * 64 + lane) * 8);
        bf16x8 b1 = *(const bf16x8*)(wfrag + ((size_t)(1 * 6 + kidx) * 64 + lane) * 8);
        bf16x8 b2 = *(const bf16x8*)(wfrag + ((size_t)(2 * 6 + kidx) * 64 + lane) * 8);
        bf16x8 b3 = *(const bf16x8*)(wfrag + ((size_t)(3 * 6 + kidx) * 64 + lane) * 8);
        acc0 = __builtin_amdgcn_mfma_f32_16x16x32_bf16(a, b0, acc0, 0, 0, 0);
        acc1 = __builtin_amdgcn_mfma_f32_16x16x32_bf16(a, b1, acc1, 0, 0, 0);
        acc2 = __builtin_amdgcn_mfma_f32_16x16x32_bf16(a, b2, acc2, 0, 0, 0);
        acc3 = __builtin_amdgcn_mfma_f32_16x16x32_bf16(a, b3, acc3, 0, 0, 0);
    }
    // epilogue: bias + activation + store (C/D: col=l16+nt*16, row=quad*4+reg)
    float accs[4][4] = {
        {acc0[0], acc0[1], acc0[2], acc0[3]},
        {acc1[0], acc1[1], acc1[2], acc1[3]},
        {acc2[0], acc2[1], acc2[2], acc2[3]},
        {acc3[0], acc3[1], acc3[2], acc3[3]},
    };
#pragma unroll
    for (int nt = 0; nt < 4; nt++) {
        int col = nt * 16 + l16;
        float bcol = bias[col];
#pragma unroll
        for (int r = 0; r < 4; r++) {
            int row = row0 + quad * 4 + r;
            float xv = accs[nt][r] + bcol;
            float v = act ? (xv > 0.f ? xv : 0.01f * xv)
                          : (xv > 0.f ? xv : expm1f(xv));
            hout[(size_t)row * 64 + col] = f2bf(v);
            if (subg && row < BSUB)
                subg[(size_t)row * 192 + subg_off + col] = v;
        }
    }
}

// ---------------- MLP head: [4096,192] -> relu 128 -> sigmoid 1 ----------------
__global__ __launch_bounds__(256) void head_kernel(
    const float* __restrict__ subg, const float* __restrict__ w1,
    const float* __restrict__ b1, const float* __restrict__ w2,
    const float* __restrict__ b2, float* __restrict__ out) {
    __shared__ float srow[4][192];
    int lane = threadIdx.x & 63, wid = threadIdx.x >> 6;
    int row = blockIdx.x * 4 + wid;
    const float* sr = subg + (size_t)row * 192;
    srow[wid][lane] = sr[lane];
    srow[wid][64 + lane] = sr[64 + lane];
    srow[wid][128 + lane] = sr[128 + lane];
    __syncthreads();
    float acc1 = b1[lane], acc2 = b1[64 + lane];
    const float* w1a = w1 + lane * 192;
    const float* w1b = w1 + (64 + lane) * 192;
    for (int k = 0; k < 192; k++) {
        float s = srow[wid][k];
        acc1 = fmaf(s, w1a[k], acc1);
        acc2 = fmaf(s, w1b[k], acc2);
    }
    acc1 = fmaxf(acc1, 0.f);
    acc2 = fmaxf(acc2, 0.f);
    float part = acc1 * w2[lane] + acc2 * w2[64 + lane];
    for (int off = 32; off; off >>= 1) part += __shfl_down(part, off, 64);
    if (lane == 0) out[row] = 1.f / (1.f + expf(-(part + b2[0])));
}

extern "C" void kernel_launch(void* const* d_in, const int* in_sizes, int n_in,
                              void* d_out, int out_size, void* d_ws, size_t ws_size,
                              hipStream_t stream) {
    const float* x     = (const float*)d_in[0];
    const int*   src   = (const int*)d_in[1];
    const int*   dst   = (const int*)d_in[2];
    const int*   etype = (const int*)d_in[3];
    const float* mask  = (const float*)d_in[4];
    const float* mask2 = (const float*)d_in[5];
    const float* lV = (const float*)d_in[6];
    const float* lC = (const float*)d_in[7];
    const float* lW = (const float*)d_in[8];
    const float* lB = (const float*)d_in[9];
    const float* gV = (const float*)d_in[10];
    const float* gC = (const float*)d_in[11];
    const float* gW = (const float*)d_in[12];
    const float* gB = (const float*)d_in[13];
    const float* w1 = (const float*)d_in[14];
    const float* b1 = (const float*)d_in[15];
    const float* w2 = (const float*)d_in[16];
    const float* b2 = (const float*)d_in[17];
    float* out = (float*)d_out;

    // workspace carve-up
    char* ws = (char*)d_ws;
    size_t off = 0;
    auto alloc = [&](size_t bytes) {
        void* p = ws + off;
        off += (bytes + 255) & ~(size_t)255;
        return p;
    };
    ushort4* h    = (ushort4*)alloc((size_t)N_NODES * 64 * 2);     // bf16 [N,64]
    ushort4* t    = (ushort4*)alloc((size_t)N_NODES * KDIM * 2);   // bf16 [N,192]
    int4*  csr    = (int4*)alloc((size_t)N_EDGES * 16);
    int*   offs   = (int*)alloc((size_t)(N_NODES + 1) * 4);
    int*   cursor = (int*)alloc((size_t)N_NODES * 4);
    int*   bsum   = (int*)alloc(512 * 4);
    u16*   wfrag  = (u16*)alloc((size_t)6 * 4 * 6 * 64 * 8 * 2);   // bf16 frag-packed W
    float* subg   = (float*)alloc((size_t)BSUB * 192 * 4);

    // CSR build (cursor doubles as count buffer)
    zero_kernel<<<N_NODES / 256, 256, 0, stream>>>(cursor, N_NODES);
    hist_kernel<<<N_EDGES / 256, 256, 0, stream>>>(dst, cursor);
    scan1_kernel<<<N_NODES / 256, 256, 0, stream>>>(cursor, offs, bsum);
    scan2_kernel<<<1, 512, 0, stream>>>(bsum);
    scan3_kernel<<<N_NODES / 256, 256, 0, stream>>>(offs, bsum, cursor);
    fill_kernel<<<N_EDGES / 256, 256, 0, stream>>>(src, dst, etype, mask, mask2,
                                                   cursor, csr);
    wpack_kernel<<<(6 * 4 * 6 * 64 + 255) / 256, 256, 0, stream>>>(lV, lW, gV, gW, wfrag);
    cvt_kernel<<<(N_NODES * 64 / 4) / 256, 256, 0, stream>>>((const float4*)x, h,
                                                             N_NODES * 64 / 4);

    const int convfrag = 4 * 6 * 64 * 8;   // u16 elements per conv
    for (int layer = 0; layer < 3; layer++) {
        // local conv (mask, elu)
        agg_kernel<<<N_NODES / 4, 256, 0, stream>>>(h, offs, csr,
                                                    lC + layer * NREL * NBASES, 0, t, N_NODES);
        gemm_kernel<<<N_NODES / 64, 256, 0, stream>>>(
            (const u16*)t, wfrag + (size_t)(layer * 2 + 0) * convfrag, lB + layer * 64,
            (u16*)h, nullptr, 0, N_NODES, 0);
        // global conv (mask2, leaky_relu); last layer only needs subgraph rows
        int nG = (layer == 2) ? BSUB : N_NODES;
        agg_kernel<<<(nG + 3) / 4, 256, 0, stream>>>(h, offs, csr,
                                                     gC + layer * NREL * NBASES, 1, t, nG);
        gemm_kernel<<<nG / 64, 256, 0, stream>>>(
            (const u16*)t, wfrag + (size_t)(layer * 2 + 1) * convfrag, gB + layer * 64,
            (u16*)h, subg, layer * 64, nG, 1);
    }
    head_kernel<<<BSUB / 4, 256, 0, stream>>>(subg, w1, b1, w2, b2, out);
}